// Round 1
// baseline (198.740 us; speedup 1.0000x reference)
//
#include <hip/hip_runtime.h>
#include <hip/hip_bf16.h>

typedef short bf16x8 __attribute__((ext_vector_type(8)));
typedef float f32x4 __attribute__((ext_vector_type(4)));

#define T_LEN 512
#define BATCH 32
#define D 512
#define M_TOT (T_LEN * BATCH) /* 16384 */
#define NLAYER 4

#define BM 128
#define BN 128
#define BK 32

// ---------------- fp32 -> bf16 convert (vectorized) ----------------
__global__ __launch_bounds__(256) void f32_to_bf16_k(const float* __restrict__ in,
                                                     __hip_bfloat16* __restrict__ out, int n) {
    int i = (blockIdx.x * 256 + threadIdx.x) * 4;
    if (i >= n) return;
    float4 v = *(const float4*)(in + i);
    __hip_bfloat16 h0 = __float2bfloat16(v.x);
    __hip_bfloat16 h1 = __float2bfloat16(v.y);
    __hip_bfloat16 h2 = __float2bfloat16(v.z);
    __hip_bfloat16 h3 = __float2bfloat16(v.w);
    ushort4 o;
    o.x = *(const unsigned short*)&h0;
    o.y = *(const unsigned short*)&h1;
    o.z = *(const unsigned short*)&h2;
    o.w = *(const unsigned short*)&h3;
    *(ushort4*)(out + i) = o;
}

// ---------------- bf16 GEMM: C[M][N] = A[M][K] * Bt[N][K]^T (fp32 out) ------
// m97 structure: 128x128 tile, 4 waves (2x2), 16x16x32 MFMA, global_load_lds.
__global__ __launch_bounds__(256) void gemm_bt(const __hip_bfloat16* __restrict__ A,
                                               const __hip_bfloat16* __restrict__ Bt,
                                               float* __restrict__ C) {
    constexpr int K = D;
    constexpr int N = D;
    __shared__ __hip_bfloat16 As[BM * BK];
    __shared__ __hip_bfloat16 Bs[BN * BK];

    const int tid  = threadIdx.x;
    const int wave = tid >> 6;
    const int lane = tid & 63;
    const int bn = blockIdx.x; // N/BN = 4
    const int bm = blockIdx.y; // M/BM = 128
    const int wm = (wave >> 1) * 64;
    const int wn = (wave & 1) * 64;

    // staging map: issue j (0,1), wave w: rows (j*4+w)*16 + lane/4, col (lane&3)*8
    const int lrow = lane >> 2;        // 0..15
    const int lcol = (lane & 3) * 8;   // 0,8,16,24

    const __hip_bfloat16* Ag = A  + (size_t)(bm * BM) * K;
    const __hip_bfloat16* Bg = Bt + (size_t)(bn * BN) * K;

    f32x4 acc[4][4] = {};

    for (int k0 = 0; k0 < K; k0 += BK) {
#pragma unroll
        for (int j = 0; j < 2; ++j) {
            const int rowA = (j * 4 + wave) * 16 + lrow;
            __builtin_amdgcn_global_load_lds(
                (const __attribute__((address_space(1))) void*)(Ag + (size_t)rowA * K + k0 + lcol),
                (__attribute__((address_space(3))) void*)(As + (j * 4 + wave) * 512),
                16, 0, 0);
            __builtin_amdgcn_global_load_lds(
                (const __attribute__((address_space(1))) void*)(Bg + (size_t)rowA * K + k0 + lcol),
                (__attribute__((address_space(3))) void*)(Bs + (j * 4 + wave) * 512),
                16, 0, 0);
        }
        __syncthreads();

        bf16x8 af[4], bfr[4];
        const int kg = (lane >> 4) * 8; // 0,8,16,24
        const int fr = lane & 15;
#pragma unroll
        for (int mi = 0; mi < 4; ++mi)
            af[mi] = *(const bf16x8*)(As + (wm + mi * 16 + fr) * BK + kg);
#pragma unroll
        for (int ni = 0; ni < 4; ++ni)
            bfr[ni] = *(const bf16x8*)(Bs + (wn + ni * 16 + fr) * BK + kg);
#pragma unroll
        for (int mi = 0; mi < 4; ++mi)
#pragma unroll
            for (int ni = 0; ni < 4; ++ni)
                acc[mi][ni] = __builtin_amdgcn_mfma_f32_16x16x32_bf16(af[mi], bfr[ni], acc[mi][ni], 0, 0, 0);
        __syncthreads();
    }

    // epilogue: C/D layout col=lane&15, row=(lane>>4)*4 + r  [m89-verified]
    const int cfr = lane & 15;
    const int cfq = lane >> 4;
#pragma unroll
    for (int mi = 0; mi < 4; ++mi) {
#pragma unroll
        for (int ni = 0; ni < 4; ++ni) {
            const int row0 = bm * BM + wm + mi * 16 + cfq * 4;
            const int col  = bn * BN + wn + ni * 16 + cfr;
#pragma unroll
            for (int r = 0; r < 4; ++r)
                C[(size_t)(row0 + r) * N + col] = acc[mi][ni][r];
        }
    }
}

// ---------------- sequential ReLU scan over T, per (b,h) channel ------------
// MODE bit0: write fp32 out, bit1: write bf16 out (next layer's GEMM input)
template <int MODE>
__global__ __launch_bounds__(256) void scan_k(const float* __restrict__ xh,
                                              const float* __restrict__ u,
                                              const float* __restrict__ b,
                                              float* __restrict__ outf,
                                              __hip_bfloat16* __restrict__ outb) {
    const int idx = blockIdx.x * 256 + threadIdx.x; // 0..16383
    const int ch  = idx & (D - 1);
    const float uu = u[ch];
    const float bb = b[ch];
    float h = 0.f;
#pragma unroll 16
    for (int t = 0; t < T_LEN; ++t) {
        const size_t off = (size_t)t * M_TOT + idx;
        const float v = xh[off] + bb;
        h = fmaxf(fmaf(uu, h, v), 0.f);
        if (MODE & 1) outf[off] = h;
        if (MODE & 2) {
            __hip_bfloat16 hb = __float2bfloat16(h);
            outb[off] = hb;
        }
    }
}

extern "C" void kernel_launch(void* const* d_in, const int* in_sizes, int n_in,
                              void* d_out, int out_size, void* d_ws, size_t ws_size,
                              hipStream_t stream) {
    const float* x = (const float*)d_in[0]; // [T, B, Din]
    const float* W = (const float*)d_in[1]; // [L, Dh, Din]
    const float* b = (const float*)d_in[2]; // [L, Dh]
    const float* u = (const float*)d_in[3]; // [L, Dh]
    float* out = (float*)d_out;             // [T, B, Dh]

    __hip_bfloat16* Wb = (__hip_bfloat16*)d_ws;                                   // 4*512*512 bf16 = 2MB
    __hip_bfloat16* Ab = (__hip_bfloat16*)((char*)d_ws + (size_t)NLAYER * D * D * 2); // 16384*512 bf16 = 16.8MB
    float* xh = out; // reuse d_out as the per-layer xh buffer

    f32_to_bf16_k<<<(NLAYER * D * D / 4 + 255) / 256, 256, 0, stream>>>(W, Wb, NLAYER * D * D);
    f32_to_bf16_k<<<(M_TOT * D / 4 + 255) / 256, 256, 0, stream>>>(x, Ab, M_TOT * D);

    for (int l = 0; l < NLAYER; ++l) {
        gemm_bt<<<dim3(D / BN, M_TOT / BM), 256, 0, stream>>>(Ab, Wb + (size_t)l * D * D, xh);
        if (l < NLAYER - 1) {
            scan_k<2><<<M_TOT / 256, 256, 0, stream>>>(xh, u + (size_t)l * D, b + (size_t)l * D,
                                                       nullptr, Ab);
        } else {
            scan_k<1><<<M_TOT / 256, 256, 0, stream>>>(xh, u + (size_t)l * D, b + (size_t)l * D,
                                                       out, nullptr);
        }
    }
}

// Round 2
// 188.161 us; speedup vs baseline: 1.0562x; 1.0562x over previous
//
#include <hip/hip_runtime.h>
#include <hip/hip_bf16.h>

typedef short bf16x8 __attribute__((ext_vector_type(8)));
typedef float f32x4 __attribute__((ext_vector_type(4)));

#define T_LEN 512
#define BATCH 32
#define D 512
#define M_TOT (T_LEN * BATCH) /* 16384 */
#define NLAYER 4

#define BM 128
#define BN 128
#define BK 32
#define NT (D / BK) /* 16 K-tiles */

// ---------------- fp32 -> bf16 convert (W and x in one launch) ----------------
__global__ __launch_bounds__(256) void convert_k(const float* __restrict__ W,
                                                 const float* __restrict__ x,
                                                 __hip_bfloat16* __restrict__ Wb,
                                                 __hip_bfloat16* __restrict__ xb) {
    const int nW = NLAYER * D * D; // 1048576, %4==0
    const int nX = M_TOT * D;      // 8388608, %4==0
    int i = (blockIdx.x * 256 + threadIdx.x) * 4;
    const float* src;
    __hip_bfloat16* dst;
    if (i < nW) {
        src = W + i;
        dst = Wb + i;
    } else {
        int k = i - nW;
        if (k >= nX) return;
        src = x + k;
        dst = xb + k;
    }
    float4 v = *(const float4*)src;
    __hip_bfloat16 h0 = __float2bfloat16(v.x);
    __hip_bfloat16 h1 = __float2bfloat16(v.y);
    __hip_bfloat16 h2 = __float2bfloat16(v.z);
    __hip_bfloat16 h3 = __float2bfloat16(v.w);
    ushort4 o;
    o.x = *(const unsigned short*)&h0;
    o.y = *(const unsigned short*)&h1;
    o.z = *(const unsigned short*)&h2;
    o.w = *(const unsigned short*)&h3;
    *(ushort4*)dst = o;
}

// ---------------- bf16 GEMM: Cb[M][N] = bf16(A[M][K] * Bt[N][K]^T + bias) -----
// 128x128 tile, 4 waves (2x2), 16x16x32 MFMA, global_load_lds,
// 2-phase LDS double-buffer (stage t+1 before computing t), XCD swizzle.
__global__ __launch_bounds__(256) void gemm_bt(const __hip_bfloat16* __restrict__ A,
                                               const __hip_bfloat16* __restrict__ Bt,
                                               const float* __restrict__ bias,
                                               __hip_bfloat16* __restrict__ Cb) {
    constexpr int K = D;
    constexpr int N = D;
    __shared__ __hip_bfloat16 As[2][BM * BK];
    __shared__ __hip_bfloat16 Bs[2][BN * BK];

    const int tid  = threadIdx.x;
    const int wave = tid >> 6;
    const int lane = tid & 63;

    // XCD-aware swizzle: grid = 512 = 8 XCDs x 64. Each XCD gets a contiguous
    // bm-range; the 4 bn-tiles of one bm are consecutive on the same XCD so the
    // A-panel (131 KB) is fetched into that XCD's L2 once.
    const int bid = blockIdx.x;      // 0..511
    const int xcd = bid & 7;
    const int j   = bid >> 3;        // 0..63
    const int bm  = xcd * 16 + (j >> 2); // 0..127
    const int bn  = j & 3;               // 0..3

    const int wm = (wave >> 1) * 64;
    const int wn = (wave & 1) * 64;

    const int lrow = lane >> 2;        // 0..15
    const int lcol = (lane & 3) * 8;   // 0,8,16,24

    const __hip_bfloat16* Ag = A  + (size_t)(bm * BM) * K;
    const __hip_bfloat16* Bg = Bt + (size_t)(bn * BN) * K;

    f32x4 acc[4][4] = {};

#define STAGE(buf, k0)                                                                             \
    do {                                                                                           \
        _Pragma("unroll") for (int jj = 0; jj < 2; ++jj) {                                         \
            const int rowA = (jj * 4 + wave) * 16 + lrow;                                          \
            __builtin_amdgcn_global_load_lds(                                                      \
                (const __attribute__((address_space(1))) void*)(Ag + (size_t)rowA * K + (k0) + lcol), \
                (__attribute__((address_space(3))) void*)(&As[buf][(jj * 4 + wave) * 512]),        \
                16, 0, 0);                                                                         \
            __builtin_amdgcn_global_load_lds(                                                      \
                (const __attribute__((address_space(1))) void*)(Bg + (size_t)rowA * K + (k0) + lcol), \
                (__attribute__((address_space(3))) void*)(&Bs[buf][(jj * 4 + wave) * 512]),        \
                16, 0, 0);                                                                         \
        }                                                                                          \
    } while (0)

#define COMPUTE(buf)                                                                               \
    do {                                                                                           \
        bf16x8 af[4], bfr[4];                                                                      \
        const int kg = (lane >> 4) * 8;                                                            \
        const int fr = lane & 15;                                                                  \
        _Pragma("unroll") for (int mi = 0; mi < 4; ++mi)                                           \
            af[mi] = *(const bf16x8*)(&As[buf][(wm + mi * 16 + fr) * BK + kg]);                    \
        _Pragma("unroll") for (int ni = 0; ni < 4; ++ni)                                           \
            bfr[ni] = *(const bf16x8*)(&Bs[buf][(wn + ni * 16 + fr) * BK + kg]);                   \
        _Pragma("unroll") for (int mi = 0; mi < 4; ++mi)                                           \
            _Pragma("unroll") for (int ni = 0; ni < 4; ++ni)                                       \
                acc[mi][ni] =                                                                      \
                    __builtin_amdgcn_mfma_f32_16x16x32_bf16(af[mi], bfr[ni], acc[mi][ni], 0, 0, 0);\
    } while (0)

    // prologue
    STAGE(0, 0);
    __syncthreads();
    int cur = 0;
    for (int kt = 1; kt < NT; ++kt) {
        STAGE(cur ^ 1, kt * BK);   // issue next tile's loads first...
        COMPUTE(cur);              // ...hide their latency under this tile's MFMA
        __syncthreads();           // drains vmcnt(0)+lgkmcnt(0): next buf ready
        cur ^= 1;
    }
    COMPUTE(cur);

    // epilogue: C/D layout col=lane&15, row=(lane>>4)*4 + r  [m89-verified]
    const int cfr = lane & 15;
    const int cfq = lane >> 4;
#pragma unroll
    for (int mi = 0; mi < 4; ++mi) {
#pragma unroll
        for (int ni = 0; ni < 4; ++ni) {
            const int row0 = bm * BM + wm + mi * 16 + cfq * 4;
            const int col  = bn * BN + wn + ni * 16 + cfr;
            const float bs = bias[col];
#pragma unroll
            for (int r = 0; r < 4; ++r) {
                __hip_bfloat16 hv = __float2bfloat16(acc[mi][ni][r] + bs);
                Cb[(size_t)(row0 + r) * N + col] = hv;
            }
        }
    }
#undef STAGE
#undef COMPUTE
}

// ---------------- sequential ReLU scan over T, per (b,h) channel ------------
// bias already folded into xh by the GEMM epilogue.
// MODE bit0: write fp32 out, bit1: write bf16 out (next layer's GEMM input)
template <int MODE>
__global__ __launch_bounds__(256) void scan_k(const __hip_bfloat16* __restrict__ xh,
                                              const float* __restrict__ u,
                                              float* __restrict__ outf,
                                              __hip_bfloat16* __restrict__ outb) {
    const int idx = blockIdx.x * 256 + threadIdx.x; // 0..16383
    const int ch  = idx & (D - 1);
    const float uu = u[ch];
    float h = 0.f;
#pragma unroll 16
    for (int t = 0; t < T_LEN; ++t) {
        const size_t off = (size_t)t * M_TOT + idx;
        const float v = __bfloat162float(xh[off]);
        h = fmaxf(fmaf(uu, h, v), 0.f);
        if (MODE & 1) outf[off] = h;
        if (MODE & 2) outb[off] = __float2bfloat16(h);
    }
}

extern "C" void kernel_launch(void* const* d_in, const int* in_sizes, int n_in,
                              void* d_out, int out_size, void* d_ws, size_t ws_size,
                              hipStream_t stream) {
    const float* x = (const float*)d_in[0]; // [T, B, Din]
    const float* W = (const float*)d_in[1]; // [L, Dh, Din]
    const float* b = (const float*)d_in[2]; // [L, Dh]
    const float* u = (const float*)d_in[3]; // [L, Dh]
    float* out = (float*)d_out;             // [T, B, Dh]

    __hip_bfloat16* Wb = (__hip_bfloat16*)d_ws;                                  // 2 MB
    __hip_bfloat16* Ab = (__hip_bfloat16*)((char*)d_ws + (size_t)NLAYER * D * D * 2); // 16.8 MB
    __hip_bfloat16* Xh = Ab + (size_t)M_TOT * D;                                 // 16.8 MB

    const int n_conv = NLAYER * D * D + M_TOT * D;
    convert_k<<<n_conv / 4 / 256, 256, 0, stream>>>(W, x, Wb, Ab);

    for (int l = 0; l < NLAYER; ++l) {
        gemm_bt<<<(M_TOT / BM) * (D / BN), 256, 0, stream>>>(Ab, Wb + (size_t)l * D * D,
                                                             b + (size_t)l * D, Xh);
        if (l < NLAYER - 1) {
            scan_k<2><<<M_TOT / 256, 256, 0, stream>>>(Xh, u + (size_t)l * D, nullptr, Ab);
        } else {
            scan_k<1><<<M_TOT / 256, 256, 0, stream>>>(Xh, u + (size_t)l * D, out, nullptr);
        }
    }
}

// Round 3
// 142.108 us; speedup vs baseline: 1.3985x; 1.3241x over previous
//
#include <hip/hip_runtime.h>
#include <hip/hip_bf16.h>

typedef short bf16x8 __attribute__((ext_vector_type(8)));
typedef float f32x4 __attribute__((ext_vector_type(4)));

#define T_LEN 512
#define BATCH 32
#define D 512
#define M_TOT (T_LEN * BATCH) /* 16384 */
#define NLAYER 4

#define BM 128
#define BN 128
#define BK 64
#define NT (D / BK) /* 8 K-tiles */

#define CH 64  /* scan chunk length */
#define NCH (T_LEN / CH) /* 8 chunks */

// ---------------- fp32 -> bf16 convert (W and x in one launch) ----------------
__global__ __launch_bounds__(256) void convert_k(const float* __restrict__ W,
                                                 const float* __restrict__ x,
                                                 __hip_bfloat16* __restrict__ Wb,
                                                 __hip_bfloat16* __restrict__ xb) {
    const int nW = NLAYER * D * D; // 1048576
    const int nX = M_TOT * D;      // 8388608
    int i = (blockIdx.x * 256 + threadIdx.x) * 4;
    const float* src;
    __hip_bfloat16* dst;
    if (i < nW) {
        src = W + i;
        dst = Wb + i;
    } else {
        int k = i - nW;
        if (k >= nX) return;
        src = x + k;
        dst = xb + k;
    }
    float4 v = *(const float4*)src;
    __hip_bfloat16 h0 = __float2bfloat16(v.x);
    __hip_bfloat16 h1 = __float2bfloat16(v.y);
    __hip_bfloat16 h2 = __float2bfloat16(v.z);
    __hip_bfloat16 h3 = __float2bfloat16(v.w);
    ushort4 o;
    o.x = *(const unsigned short*)&h0;
    o.y = *(const unsigned short*)&h1;
    o.z = *(const unsigned short*)&h2;
    o.w = *(const unsigned short*)&h3;
    *(ushort4*)dst = o;
}

// ---------------- bf16 GEMM: Cb[M][N] = bf16(A[M][K] * Bt[N][K]^T + bias) -----
// 128x128 tile, 4 waves (2x2), 16x16x32 MFMA, BK=64, global_load_lds with
// source-pre-swizzled chunk XOR (LDS dest linear, read side applies same XOR),
// 2-phase double-buffer, XCD-aware block swizzle.
//
// LDS layout: row-major [128 rows][64 cols] bf16 = 128B rows = 8 chunks of 16B.
// Swizzle: LDS(row, cp) holds global chunk (cp ^ (row&7)). Read of global
// chunk c at row r -> LDS chunk c ^ (r&7). Bank-group = chunk index, so each
// ds_read_b128 spreads 64 lanes uniformly over all 8 groups (8 lanes each =
// the 1KB/128B service floor, conflict-free).
__global__ __launch_bounds__(256) void gemm_bt(const __hip_bfloat16* __restrict__ A,
                                               const __hip_bfloat16* __restrict__ Bt,
                                               const float* __restrict__ bias,
                                               __hip_bfloat16* __restrict__ Cb) {
    constexpr int K = D;
    constexpr int N = D;
    __shared__ __hip_bfloat16 As[2][BM * BK]; // 16KB per buf
    __shared__ __hip_bfloat16 Bs[2][BN * BK]; // 16KB per buf  (total 64KB)

    const int tid  = threadIdx.x;
    const int wave = tid >> 6;
    const int lane = tid & 63;

    // XCD-aware swizzle: grid = 512 = 8 XCDs x 64; 4 bn-tiles of one bm stay
    // on one XCD so the A-panel is fetched into that XCD's L2 once.
    const int bid = blockIdx.x;
    const int xcd = bid & 7;
    const int j   = bid >> 3;
    const int bm  = xcd * 16 + (j >> 2);
    const int bn  = j & 3;

    const int wm = (wave >> 1) * 64;
    const int wn = (wave & 1) * 64;

    // staging map per wave-issue: 8 rows x 8 chunks; lane -> row lane>>3, chunk lane&7
    const int srow = lane >> 3;                                // 0..7 (== row&7)
    const int scol = ((lane & 7) ^ srow) * 8;                  // pre-swizzled source col (elements)

    const __hip_bfloat16* Ag = A  + (size_t)(bm * BM) * K;
    const __hip_bfloat16* Bg = Bt + (size_t)(bn * BN) * K;

    f32x4 acc[4][4] = {};

#define STAGE(buf, k0)                                                                               \
    do {                                                                                             \
        _Pragma("unroll") for (int jj = 0; jj < 4; ++jj) {                                           \
            const int rbase = (jj * 4 + wave) * 8;                                                   \
            __builtin_amdgcn_global_load_lds(                                                        \
                (const __attribute__((address_space(1))) void*)(Ag + (size_t)(rbase + srow) * K + (k0) + scol), \
                (__attribute__((address_space(3))) void*)(&As[buf][rbase * BK]), 16, 0, 0);          \
            __builtin_amdgcn_global_load_lds(                                                        \
                (const __attribute__((address_space(1))) void*)(Bg + (size_t)(rbase + srow) * K + (k0) + scol), \
                (__attribute__((address_space(3))) void*)(&Bs[buf][rbase * BK]), 16, 0, 0);          \
        }                                                                                            \
    } while (0)

#define COMPUTE(buf)                                                                                 \
    do {                                                                                             \
        bf16x8 af[4][2], bv[4][2];                                                                   \
        const int fr = lane & 15;                                                                    \
        const int kq = lane >> 4; /* 0..3 */                                                         \
        _Pragma("unroll") for (int mi = 0; mi < 4; ++mi) {                                           \
            const int r = wm + mi * 16 + fr;                                                         \
            _Pragma("unroll") for (int kh = 0; kh < 2; ++kh) {                                       \
                const int c = ((kh * 4 + kq) ^ (fr & 7)) * 8;                                        \
                af[mi][kh] = *(const bf16x8*)(&As[buf][r * BK + c]);                                 \
            }                                                                                        \
        }                                                                                            \
        _Pragma("unroll") for (int ni = 0; ni < 4; ++ni) {                                           \
            const int r = wn + ni * 16 + fr;                                                         \
            _Pragma("unroll") for (int kh = 0; kh < 2; ++kh) {                                       \
                const int c = ((kh * 4 + kq) ^ (fr & 7)) * 8;                                        \
                bv[ni][kh] = *(const bf16x8*)(&Bs[buf][r * BK + c]);                                 \
            }                                                                                        \
        }                                                                                            \
        _Pragma("unroll") for (int kh = 0; kh < 2; ++kh)                                             \
            _Pragma("unroll") for (int mi = 0; mi < 4; ++mi)                                         \
                _Pragma("unroll") for (int ni = 0; ni < 4; ++ni)                                     \
                    acc[mi][ni] = __builtin_amdgcn_mfma_f32_16x16x32_bf16(af[mi][kh], bv[ni][kh],    \
                                                                          acc[mi][ni], 0, 0, 0);    \
    } while (0)

    STAGE(0, 0);
    __syncthreads();
    int cur = 0;
#pragma unroll
    for (int kt = 1; kt < NT; ++kt) {
        STAGE(cur ^ 1, kt * BK); // issue next tile's loads first...
        COMPUTE(cur);            // ...hide their latency under this tile's MFMA
        __syncthreads();
        cur ^= 1;
    }
    COMPUTE(cur);

    // epilogue: C/D layout col=lane&15, row=(lane>>4)*4 + r  [m89-verified]
    const int cfr = lane & 15;
    const int cfq = lane >> 4;
#pragma unroll
    for (int mi = 0; mi < 4; ++mi) {
#pragma unroll
        for (int ni = 0; ni < 4; ++ni) {
            const int row0 = bm * BM + wm + mi * 16 + cfq * 4;
            const int col  = bn * BN + wn + ni * 16 + cfr;
            const float bs = bias[col];
#pragma unroll
            for (int r = 0; r < 4; ++r) {
                __hip_bfloat16 hv = __float2bfloat16(acc[mi][ni][r] + bs);
                Cb[(size_t)(row0 + r) * N + col] = hv;
            }
        }
    }
#undef STAGE
#undef COMPUTE
}

// ---------------- parallel scan: h_t = max(0, a_t + u*h_{t-1}) ---------------
// Chunked associative decomposition: per chunk, F(h) = max(m, d + e*h) with
//   m' = max(0, a + u*m)   (== the recurrence restarted from 0)
//   d' = a + u*d           (linear part, no clipping; |d| <= CH*max|a|)
//   e  = u^CH
// Valid on the h>=0 domain (all real states are relu outputs or h0=0).

// phase 1: per (chunk, channel) compute (m, d)
__global__ __launch_bounds__(256) void scan1_k(const __hip_bfloat16* __restrict__ xh,
                                               const float* __restrict__ u,
                                               float2* __restrict__ md) {
    const int gid = blockIdx.x * 256 + threadIdx.x; // 0..131071
    const int idx = gid & (M_TOT - 1);
    const int c   = gid >> 14; // 0..7 (uniform per block)
    const float uu = u[idx & (D - 1)];
    float m = 0.f, d = 0.f;
    const __hip_bfloat16* p = xh + (size_t)c * CH * M_TOT + idx;
#pragma unroll 8
    for (int t = 0; t < CH; ++t) {
        const float a = __bfloat162float(p[(size_t)t * M_TOT]);
        m = fmaxf(fmaf(uu, m, a), 0.f);
        d = fmaf(uu, d, a);
    }
    md[gid] = make_float2(m, d);
}

// phase 2: combine prior chunks' (m,d) then replay this chunk writing outputs.
// MODE bit0: fp32 out, bit1: bf16 out (next layer's GEMM input)
template <int MODE>
__global__ __launch_bounds__(256) void scan2_k(const __hip_bfloat16* __restrict__ xh,
                                               const float* __restrict__ u,
                                               const float2* __restrict__ md,
                                               float* __restrict__ outf,
                                               __hip_bfloat16* __restrict__ outb) {
    const int gid = blockIdx.x * 256 + threadIdx.x;
    const int idx = gid & (M_TOT - 1);
    const int c   = gid >> 14; // uniform per block -> combine loop non-divergent
    const float uu = u[idx & (D - 1)];
    float e = uu * uu; // u^2
    e *= e; e *= e; e *= e; e *= e; e *= e; // u^64 == u^CH
    float h = 0.f;
    for (int jj = 0; jj < c; ++jj) {
        const float2 v = md[jj * M_TOT + idx];
        h = fmaxf(v.x, fmaf(e, h, v.y)); // h = F_jj(h) = max(m, d + e*h)
    }
    const __hip_bfloat16* p = xh + (size_t)c * CH * M_TOT + idx;
    float* qf = outf + (size_t)c * CH * M_TOT + idx;
    __hip_bfloat16* qb = outb + (size_t)c * CH * M_TOT + idx;
#pragma unroll 8
    for (int t = 0; t < CH; ++t) {
        const size_t off = (size_t)t * M_TOT;
        const float a = __bfloat162float(p[off]);
        h = fmaxf(fmaf(uu, h, a), 0.f);
        if (MODE & 1) qf[off] = h;
        if (MODE & 2) qb[off] = __float2bfloat16(h);
    }
}

extern "C" void kernel_launch(void* const* d_in, const int* in_sizes, int n_in,
                              void* d_out, int out_size, void* d_ws, size_t ws_size,
                              hipStream_t stream) {
    const float* x = (const float*)d_in[0]; // [T, B, Din]
    const float* W = (const float*)d_in[1]; // [L, Dh, Din]
    const float* b = (const float*)d_in[2]; // [L, Dh]
    const float* u = (const float*)d_in[3]; // [L, Dh]
    float* out = (float*)d_out;             // [T, B, Dh]

    __hip_bfloat16* Wb = (__hip_bfloat16*)d_ws;                                       // 2 MB
    __hip_bfloat16* Ab = (__hip_bfloat16*)((char*)d_ws + (size_t)NLAYER * D * D * 2); // 16.8 MB
    __hip_bfloat16* Xh = Ab + (size_t)M_TOT * D;                                      // 16.8 MB
    float2* md = (float2*)(Xh + (size_t)M_TOT * D);                                   // 1 MB

    const int n_conv = NLAYER * D * D + M_TOT * D;
    convert_k<<<n_conv / 4 / 256, 256, 0, stream>>>(W, x, Wb, Ab);

    for (int l = 0; l < NLAYER; ++l) {
        gemm_bt<<<(M_TOT / BM) * (D / BN), 256, 0, stream>>>(Ab, Wb + (size_t)l * D * D,
                                                             b + (size_t)l * D, Xh);
        scan1_k<<<M_TOT * NCH / 256, 256, 0, stream>>>(Xh, u + (size_t)l * D, md);
        if (l < NLAYER - 1) {
            scan2_k<2><<<M_TOT * NCH / 256, 256, 0, stream>>>(Xh, u + (size_t)l * D, md,
                                                              nullptr, Ab);
        } else {
            scan2_k<1><<<M_TOT * NCH / 256, 256, 0, stream>>>(Xh, u + (size_t)l * D, md,
                                                              out, nullptr);
        }
    }
}

// Round 4
// 124.892 us; speedup vs baseline: 1.5913x; 1.1378x over previous
//
#include <hip/hip_runtime.h>
#include <hip/hip_bf16.h>

typedef short bf16x8 __attribute__((ext_vector_type(8)));
typedef float f32x4 __attribute__((ext_vector_type(4)));

#define T_LEN 512
#define BATCH 32
#define D 512
#define M_TOT (T_LEN * BATCH) /* 16384 */
#define NLAYER 4

#define BM 128
#define BN 128
#define BK 64
#define NT (D / BK) /* 8 K-tiles */
#define EP 72       /* epilogue LDS row stride (elems): 144B, 16B-aligned, read-conflict-free */

#define CH 64            /* scan chunk length */
#define NCH (T_LEN / CH) /* 8 chunks */

// ---------------- fp32 -> bf16 convert (W and x in one launch) ----------------
__global__ __launch_bounds__(256) void convert_k(const float* __restrict__ W,
                                                 const float* __restrict__ x,
                                                 __hip_bfloat16* __restrict__ Wb,
                                                 __hip_bfloat16* __restrict__ xb) {
    const int nW = NLAYER * D * D; // 1048576
    const int nX = M_TOT * D;      // 8388608
    int i = (blockIdx.x * 256 + threadIdx.x) * 4;
    const float* src;
    __hip_bfloat16* dst;
    if (i < nW) {
        src = W + i;
        dst = Wb + i;
    } else {
        int k = i - nW;
        if (k >= nX) return;
        src = x + k;
        dst = xb + k;
    }
    float4 v = *(const float4*)src;
    __hip_bfloat16 h0 = __float2bfloat16(v.x);
    __hip_bfloat16 h1 = __float2bfloat16(v.y);
    __hip_bfloat16 h2 = __float2bfloat16(v.z);
    __hip_bfloat16 h3 = __float2bfloat16(v.w);
    ushort4 o;
    o.x = *(const unsigned short*)&h0;
    o.y = *(const unsigned short*)&h1;
    o.z = *(const unsigned short*)&h2;
    o.w = *(const unsigned short*)&h3;
    *(ushort4*)dst = o;
}

// ---------------- bf16 GEMM: Cb[M][N] = bf16(A[M][K] * Bt[N][K]^T + bias) -----
// 128x128 tile, 4 waves (2x2), 16x16x32 MFMA, BK=64, global_load_lds with
// source-pre-swizzled chunk XOR (LDS dest linear, read side same XOR),
// 2-phase double-buffer, XCD-aware block swizzle, LDS-transposed epilogue
// producing coalesced 128B bf16x8 stores.
__global__ __launch_bounds__(256) void gemm_bt(const __hip_bfloat16* __restrict__ A,
                                               const __hip_bfloat16* __restrict__ Bt,
                                               const float* __restrict__ bias,
                                               __hip_bfloat16* __restrict__ Cb) {
    constexpr int K = D;
    constexpr int N = D;
    __shared__ __hip_bfloat16 smem[4 * BM * BK]; // 64KB
    __hip_bfloat16* const AsP[2] = {smem, smem + BM * BK};
    __hip_bfloat16* const BsP[2] = {smem + 2 * BM * BK, smem + 3 * BM * BK};

    const int tid  = threadIdx.x;
    const int wave = tid >> 6;
    const int lane = tid & 63;

    // XCD-aware swizzle: grid = 512 = 8 XCDs x 64; 4 bn-tiles of one bm stay
    // on one XCD so the A-panel is fetched into that XCD's L2 once.
    const int bid = blockIdx.x;
    const int xcd = bid & 7;
    const int j   = bid >> 3;
    const int bm  = xcd * 16 + (j >> 2);
    const int bn  = j & 3;

    const int wm = (wave >> 1) * 64;
    const int wn = (wave & 1) * 64;

    // staging map per wave-issue: 8 rows x 8 chunks; lane -> row lane>>3, chunk lane&7
    const int srow = lane >> 3;               // 0..7 (== row&7)
    const int scol = ((lane & 7) ^ srow) * 8; // pre-swizzled source col (elements)

    const __hip_bfloat16* Ag = A  + (size_t)(bm * BM) * K;
    const __hip_bfloat16* Bg = Bt + (size_t)(bn * BN) * K;

    f32x4 acc[4][4] = {};

#define STAGE(buf, k0)                                                                               \
    do {                                                                                             \
        _Pragma("unroll") for (int jj = 0; jj < 4; ++jj) {                                           \
            const int rbase = (jj * 4 + wave) * 8;                                                   \
            __builtin_amdgcn_global_load_lds(                                                        \
                (const __attribute__((address_space(1))) void*)(Ag + (size_t)(rbase + srow) * K + (k0) + scol), \
                (__attribute__((address_space(3))) void*)(&AsP[buf][rbase * BK]), 16, 0, 0);         \
            __builtin_amdgcn_global_load_lds(                                                        \
                (const __attribute__((address_space(1))) void*)(Bg + (size_t)(rbase + srow) * K + (k0) + scol), \
                (__attribute__((address_space(3))) void*)(&BsP[buf][rbase * BK]), 16, 0, 0);         \
        }                                                                                            \
    } while (0)

#define COMPUTE(buf)                                                                                 \
    do {                                                                                             \
        bf16x8 af[4][2], bv[4][2];                                                                   \
        const int fr = lane & 15;                                                                    \
        const int kq = lane >> 4; /* 0..3 */                                                         \
        _Pragma("unroll") for (int mi = 0; mi < 4; ++mi) {                                           \
            const int r = wm + mi * 16 + fr;                                                         \
            _Pragma("unroll") for (int kh = 0; kh < 2; ++kh) {                                       \
                const int c = ((kh * 4 + kq) ^ (fr & 7)) * 8;                                        \
                af[mi][kh] = *(const bf16x8*)(&AsP[buf][r * BK + c]);                                \
            }                                                                                        \
        }                                                                                            \
        _Pragma("unroll") for (int ni = 0; ni < 4; ++ni) {                                           \
            const int r = wn + ni * 16 + fr;                                                         \
            _Pragma("unroll") for (int kh = 0; kh < 2; ++kh) {                                       \
                const int c = ((kh * 4 + kq) ^ (fr & 7)) * 8;                                        \
                bv[ni][kh] = *(const bf16x8*)(&BsP[buf][r * BK + c]);                                \
            }                                                                                        \
        }                                                                                            \
        _Pragma("unroll") for (int kh = 0; kh < 2; ++kh)                                             \
            _Pragma("unroll") for (int mi = 0; mi < 4; ++mi)                                         \
                _Pragma("unroll") for (int ni = 0; ni < 4; ++ni)                                     \
                    acc[mi][ni] = __builtin_amdgcn_mfma_f32_16x16x32_bf16(af[mi][kh], bv[ni][kh],    \
                                                                          acc[mi][ni], 0, 0, 0);    \
    } while (0)

    STAGE(0, 0);
    __syncthreads();
    int cur = 0;
#pragma unroll
    for (int kt = 1; kt < NT; ++kt) {
        STAGE(cur ^ 1, kt * BK); // issue next tile's loads first...
        COMPUTE(cur);            // ...hide their latency under this tile's MFMA
        __syncthreads();
        cur ^= 1;
    }
    COMPUTE(cur);
    __syncthreads(); // all waves done with As/Bs before LDS reuse

    // ---- epilogue: stage wave's 64x64 tile in LDS, store coalesced rows ----
    // C/D layout: col=lane&15, row=(lane>>4)*4 + r  [m89-verified]
    {
        __hip_bfloat16* S = smem + wave * (64 * EP);
        const int cfr = lane & 15;
        const int cfq = lane >> 4;
        float bs[4];
#pragma unroll
        for (int ni = 0; ni < 4; ++ni) bs[ni] = bias[bn * BN + wn + ni * 16 + cfr];
#pragma unroll
        for (int mi = 0; mi < 4; ++mi)
#pragma unroll
            for (int ni = 0; ni < 4; ++ni)
#pragma unroll
                for (int r = 0; r < 4; ++r)
                    S[(mi * 16 + cfq * 4 + r) * EP + ni * 16 + cfr] =
                        __float2bfloat16(acc[mi][ni][r] + bs[ni]);
        // wave-local read-back (lgkmcnt deps keep ordering; no barrier needed)
        const int rq = lane >> 3;        // 0..7
        const int cl = (lane & 7) * 8;   // 0..56
#pragma unroll
        for (int p = 0; p < 8; ++p) {
            const int lr = p * 8 + rq;
            bf16x8 v = *(const bf16x8*)(S + lr * EP + cl);
            *(bf16x8*)(&Cb[(size_t)(bm * BM + wm + lr) * N + bn * BN + wn + cl]) = v;
        }
    }
#undef STAGE
#undef COMPUTE
}

// ---------------- fused parallel scan: h_t = max(0, a_t + u*h_{t-1}) ---------
// Chunk decomposition (h>=0 domain): F_c(h) = max(m, d + e*h),
//   m = relu-scan restarted from 0, d = linear part, e = u^CH.
// One kernel: block = 8 chunks x 64 channels (512 thr). Each thread keeps its
// chunk's 64 bf16 xh values in registers, exchanges (m,d) via LDS, combines
// (wave-uniform trip count), replays from registers. Xh read ONCE.
// MODE bit0: fp32 out, bit1: bf16 out (next layer's GEMM input)
template <int MODE>
__global__ __launch_bounds__(512) void scan_k(const __hip_bfloat16* __restrict__ xh,
                                              const float* __restrict__ u,
                                              float* __restrict__ outf,
                                              __hip_bfloat16* __restrict__ outb) {
    __shared__ float2 md[NCH][64];
    const int i   = threadIdx.x & 63;
    const int c   = threadIdx.x >> 6; // 0..7, uniform per wave
    const int idx = blockIdx.x * 64 + i;
    const float uu = u[idx & (D - 1)];

    const __hip_bfloat16* p = xh + (size_t)c * CH * M_TOT + idx;
    unsigned short xv[CH];
#pragma unroll
    for (int t = 0; t < CH; ++t) xv[t] = *(const unsigned short*)(p + (size_t)t * M_TOT);

    float m = 0.f, d = 0.f;
#pragma unroll
    for (int t = 0; t < CH; ++t) {
        const float a = __uint_as_float(((unsigned int)xv[t]) << 16);
        m = fmaxf(fmaf(uu, m, a), 0.f);
        d = fmaf(uu, d, a);
    }
    md[c][i] = make_float2(m, d);
    __syncthreads();

    float e = uu * uu;                       // u^2
    e *= e; e *= e; e *= e; e *= e; e *= e;  // u^64 == u^CH
    float h = 0.f;
    for (int jj = 0; jj < c; ++jj) {
        const float2 v = md[jj][i];
        h = fmaxf(v.x, fmaf(e, h, v.y)); // h = F_jj(h)
    }

    float* qf = outf + (size_t)c * CH * M_TOT + idx;
    __hip_bfloat16* qb = outb + (size_t)c * CH * M_TOT + idx;
#pragma unroll
    for (int t = 0; t < CH; ++t) {
        const float a = __uint_as_float(((unsigned int)xv[t]) << 16);
        h = fmaxf(fmaf(uu, h, a), 0.f);
        if (MODE & 1) qf[(size_t)t * M_TOT] = h;
        if (MODE & 2) qb[(size_t)t * M_TOT] = __float2bfloat16(h);
    }
}

extern "C" void kernel_launch(void* const* d_in, const int* in_sizes, int n_in,
                              void* d_out, int out_size, void* d_ws, size_t ws_size,
                              hipStream_t stream) {
    const float* x = (const float*)d_in[0]; // [T, B, Din]
    const float* W = (const float*)d_in[1]; // [L, Dh, Din]
    const float* b = (const float*)d_in[2]; // [L, Dh]
    const float* u = (const float*)d_in[3]; // [L, Dh]
    float* out = (float*)d_out;             // [T, B, Dh]

    __hip_bfloat16* Wb = (__hip_bfloat16*)d_ws;                                       // 2 MB
    __hip_bfloat16* Ab = (__hip_bfloat16*)((char*)d_ws + (size_t)NLAYER * D * D * 2); // 16.8 MB
    __hip_bfloat16* Xh = Ab + (size_t)M_TOT * D;                                      // 16.8 MB

    const int n_conv = NLAYER * D * D + M_TOT * D;
    convert_k<<<n_conv / 4 / 256, 256, 0, stream>>>(W, x, Wb, Ab);

    for (int l = 0; l < NLAYER; ++l) {
        gemm_bt<<<(M_TOT / BM) * (D / BN), 256, 0, stream>>>(Ab, Wb + (size_t)l * D * D,
                                                             b + (size_t)l * D, Xh);
        if (l < NLAYER - 1) {
            scan_k<2><<<M_TOT / 64, 512, 0, stream>>>(Xh, u + (size_t)l * D, nullptr, Ab);
        } else {
            scan_k<1><<<M_TOT / 64, 512, 0, stream>>>(Xh, u + (size_t)l * D, out, nullptr);
        }
    }
}